// Round 5
// baseline (184.001 us; speedup 1.0000x reference)
//
#include <hip/hip_runtime.h>
#include <math.h>

#define NBATCH 8192
#define NNODE  25
#define DIN    256
#define NH     8
#define NF     32
#define HF     256    // NH*NF
#define NE     48
#define NT     73     // NE + NNODE (self loops)
#define DMAX   12     // padded per-node in-degree after dedup (actual max ~7)
#define NEG_SLOPE 0.2f

// d_ws: [0,139264) bf16 Waug frags (17*8*64*8 shorts);
//       [139264, +NNODE*DMAX*4) packed CSR entries: src | (mult<<8), -1 = pad
#define WS_CSR_OFF 139264

typedef __bf16 bf16x8 __attribute__((ext_vector_type(8)));
typedef float  f32x4  __attribute__((ext_vector_type(4)));

static __device__ __forceinline__ unsigned short f2bf(float f) {
    unsigned int u = __float_as_uint(f);
    return (unsigned short)((u + 0x7fffu + ((u >> 16) & 1u)) >> 16);
}

// ---- prep: pack Waug B-frags + build deduped padded CSR. Once per launch. ----
__global__ void prep(const float* __restrict__ W,
                     const float* __restrict__ a_src,
                     const float* __restrict__ a_dst,
                     const int*   __restrict__ edges,
                     unsigned short* __restrict__ wf,
                     int* __restrict__ csr) {
    const int blk = blockIdx.x;
    if (blk < 34) {
        const int tid  = blk * 256 + threadIdx.x;   // 0..8703 == 17*8*64
        const int lane = tid & 63;
        const int ks   = (tid >> 6) & 7;
        const int ct   = tid >> 9;
        const int k0   = ks * 32 + (lane >> 4) * 8;
        if (ct < 16) {
            const int col = ct * 16 + (lane & 15);
#pragma unroll
            for (int j = 0; j < 8; ++j)
                wf[tid * 8 + j] = f2bf(W[(k0 + j) * HF + col]);
        } else {
            const int hp = lane & 15;
            const float* av = (hp < 8) ? (a_src + hp * NF) : (a_dst + (hp - 8) * NF);
            const int wc = (hp & 7) * NF;
#pragma unroll
            for (int j = 0; j < 8; ++j) {
                float s = 0.f;
                for (int f = 0; f < NF; ++f)
                    s = fmaf(W[(k0 + j) * HF + wc + f], av[f], s);
                wf[tid * 8 + j] = f2bf(s);
            }
        }
    } else {
        __shared__ int cnt[NNODE];
        __shared__ int lst[NNODE][DMAX];
        const int t = threadIdx.x;
        if (t < NNODE) cnt[t] = 0;
        __syncthreads();
        if (t < NT) {
            const int s = (t < NE) ? edges[t]      : (t - NE);
            const int d = (t < NE) ? edges[NE + t] : (t - NE);
            const int idx = atomicAdd(&cnt[d], 1);
            if (idx < DMAX) lst[d][idx] = s;
        }
        __syncthreads();
        if (t < NNODE) {
            const int c = min(cnt[t], DMAX);
            int outv[DMAX];
            int oc = 0;
            for (int i = 0; i < c; ++i) {
                const int s = lst[t][i];
                bool dup = false;
                for (int j = 0; j < oc; ++j)
                    if ((outv[j] & 0xff) == s) { outv[j] += 256; dup = true; break; }
                if (!dup) outv[oc++] = s | 256;   // mult = 1
            }
            for (int i = 0; i < DMAX; ++i)
                csr[t * DMAX + i] = (i < oc) ? outv[i] : -1;
        }
    }
}

__global__ __launch_bounds__(256, 4)
void gat_main(const float* __restrict__ X,
              const unsigned short* __restrict__ wf,
              const int*   __restrict__ csrg,
              const float* __restrict__ bias,
              float*       __restrict__ out)
{
    // phase 1: sA (16 KB, swizzled bf16 A-tile) | phase 2: sHT (16 KB h^T) + sP (16 KB alpha)
    __shared__ __align__(16) unsigned char uni[32768];
    unsigned char* sA  = uni;                 // [32 rows][512 B]
    unsigned char* sHT = uni;                 // [256 cols][64 B] (k-granule swizzled)
    unsigned char* sP  = uni + 16384;         // [8 heads][32 n][64 B] (src-granule swizzled)
    __shared__ float sAs[NNODE][NH];
    __shared__ float sAd[NNODE][NH];
    __shared__ int   sSrcPad[NNODE * DMAX];
    __shared__ float sBias[HF];

    const int t = threadIdx.x;
    const int b = blockIdx.x;
    const int w = t >> 6;
    const int l = t & 63;

    // ---- stage CSR + bias ----
    for (int i = t; i < NNODE * DMAX; i += 256) sSrcPad[i] = csrg[i];
    sBias[t] = bias[t];

    // ---- zero padded A rows 25..31 ----
    if (t < 224) {
        const int row = 25 + (t >> 5);
        *(uint4*)(sA + row * 512 + (t & 31) * 16) = make_uint4(0, 0, 0, 0);
    }

    // ---- stage X tile: f32 -> bf16, XOR-swizzled ----
    const float* Xb = X + (size_t)b * (NNODE * DIN);
#pragma unroll
    for (int i = 0; i < 7; ++i) {
        const int n = w + 4 * i;
        if (n < NNODE) {
            const float4 x = *(const float4*)(Xb + n * DIN + l * 4);
            const unsigned int lo = (unsigned int)f2bf(x.x) | ((unsigned int)f2bf(x.y) << 16);
            const unsigned int hi = (unsigned int)f2bf(x.z) | ((unsigned int)f2bf(x.w) << 16);
            const int kblk = l >> 1;
            const int addr = n * 512 + (((kblk ^ (n & 7)) << 4) | ((l & 1) << 3));
            *(uint2*)(sA + addr) = make_uint2(lo, hi);
        }
    }
    __syncthreads();

    // ---- GEMM1: wave w owns cols [w*64, w*64+64); wave 0 also the logits tile ----
    const int r  = l & 15;
    const int kq = l >> 4;
    f32x4 acc[2][4];
    f32x4 accL[2];
#pragma unroll
    for (int m = 0; m < 2; ++m) {
        accL[m] = f32x4{0.f, 0.f, 0.f, 0.f};
#pragma unroll
        for (int c = 0; c < 4; ++c) acc[m][c] = f32x4{0.f, 0.f, 0.f, 0.f};
    }

#pragma unroll
    for (int ks = 0; ks < 8; ++ks) {
        bf16x8 af[2];
#pragma unroll
        for (int m = 0; m < 2; ++m) {
            const int row  = 16 * m + r;
            const int kblk = ks * 4 + kq;
            af[m] = *(const bf16x8*)(sA + row * 512 + ((kblk ^ (row & 7)) << 4));
        }
#pragma unroll
        for (int c = 0; c < 4; ++c) {
            const int ct = w * 4 + c;
            const bf16x8 bfr = *(const bf16x8*)(wf + ((size_t)(ct * 8 + ks) * 64 + l) * 8);
            acc[0][c] = __builtin_amdgcn_mfma_f32_16x16x32_bf16(af[0], bfr, acc[0][c], 0, 0, 0);
            acc[1][c] = __builtin_amdgcn_mfma_f32_16x16x32_bf16(af[1], bfr, acc[1][c], 0, 0, 0);
        }
        if (w == 0) {
            const bf16x8 bfr = *(const bf16x8*)(wf + ((size_t)(16 * 8 + ks) * 64 + l) * 8);
            accL[0] = __builtin_amdgcn_mfma_f32_16x16x32_bf16(af[0], bfr, accL[0], 0, 0, 0);
            accL[1] = __builtin_amdgcn_mfma_f32_16x16x32_bf16(af[1], bfr, accL[1], 0, 0, 0);
        }
    }
    __syncthreads();   // sA dead; union becomes sHT + sP

    // ---- C-frags -> sHT (transposed, swizzled); w0 logits -> sAs/sAd; zero sP ----
    // C-frag (m,c): rows 16m+4kq..+3 at col (w*4+c)*16+r -> 8 B at byte 32m+8kq of col.
#pragma unroll
    for (int m = 0; m < 2; ++m)
#pragma unroll
        for (int c = 0; c < 4; ++c) {
            const int col = (w * 4 + c) * 16 + r;
            const unsigned int lo = (unsigned int)f2bf(acc[m][c][0]) | ((unsigned int)f2bf(acc[m][c][1]) << 16);
            const unsigned int hi = (unsigned int)f2bf(acc[m][c][2]) | ((unsigned int)f2bf(acc[m][c][3]) << 16);
            const int gi   = 2 * m + (kq >> 1);
            const int addr = col * 64 + ((gi ^ ((col >> 1) & 3)) << 4) + (kq & 1) * 8;
            *(uint2*)(sHT + addr) = make_uint2(lo, hi);
        }
    if (w == 0) {
#pragma unroll
        for (int m = 0; m < 2; ++m)
#pragma unroll
            for (int q = 0; q < 4; ++q) {
                const int row = 16 * m + kq * 4 + q;
                if (row < NNODE) {
                    if (r < 8) sAs[row][r]     = accL[m][q];
                    else       sAd[row][r - 8] = accL[m][q];
                }
            }
    }
    {   // zero sP: 16 KB / 256 threads = 64 B each
        const uint4 z = make_uint4(0, 0, 0, 0);
        *(uint4*)(sP + t * 64)      = z;
        *(uint4*)(sP + t * 64 + 16) = z;
        *(uint4*)(sP + t * 64 + 32) = z;
        *(uint4*)(sP + t * 64 + 48) = z;
    }
    __syncthreads();

    // ---- softmax per (n,h): scatter normalized alpha (bf16) into sP ----
    if (t < NNODE * NH) {
        const int n = t >> 3, h = t & 7;
        const float adn = sAd[n][h];
        float e[DMAX];
        int   sv[DMAX];
        float s = 0.f;
#pragma unroll
        for (int d = 0; d < DMAX; ++d) {
            const int ent = sSrcPad[n * DMAX + d];
            sv[d] = ent;
            const int src = (ent < 0) ? 0 : (ent & 0xff);
            float sc = sAs[src][h] + adn;
            sc = (sc > 0.f) ? sc : NEG_SLOPE * sc;          // leaky relu (shift-inv softmax)
            const float p = (ent < 0) ? 0.f : (float)(ent >> 8) * __expf(sc);
            e[d] = p;
            s += p;
        }
        const float inv = 1.f / (s + 1e-16f);
#pragma unroll
        for (int d = 0; d < DMAX; ++d) {
            const int ent = sv[d];
            if (ent >= 0) {
                const int src  = ent & 0xff;
                const int addr = h * 2048 + n * 64 + ((((src >> 3)) ^ ((n >> 1) & 3)) << 4) + (src & 7) * 2;
                *(unsigned short*)(sP + addr) = f2bf(e[d] * inv);
            }
        }
    }
    __syncthreads();

    // ---- GEMM2 (aggregate): out_h[n][f] = sum_src P_h[n][src] * h[src][h*32+f] ----
    // wave w handles heads 2w, 2w+1; per head: 2 m-tiles x 2 col-tiles, K=32 in one MFMA.
    f32x4 oacc[2][2][2];
#pragma unroll
    for (int hh = 0; hh < 2; ++hh)
#pragma unroll
        for (int m = 0; m < 2; ++m)
#pragma unroll
            for (int ct = 0; ct < 2; ++ct)
                oacc[hh][m][ct] = f32x4{0.f, 0.f, 0.f, 0.f};

    const int sxa = (r >> 1) & 3;   // ((16m+r)>>1)&3 == (r>>1)&3
#pragma unroll
    for (int hh = 0; hh < 2; ++hh) {
        const int h = 2 * w + hh;
        bf16x8 pa[2], hb[2];
#pragma unroll
        for (int m = 0; m < 2; ++m)
            pa[m] = *(const bf16x8*)(sP + h * 2048 + (16 * m + r) * 64 + ((kq ^ sxa) << 4));
#pragma unroll
        for (int ct = 0; ct < 2; ++ct) {
            const int col = h * 32 + ct * 16 + r;
            hb[ct] = *(const bf16x8*)(sHT + col * 64 + ((kq ^ ((col >> 1) & 3)) << 4));
        }
#pragma unroll
        for (int m = 0; m < 2; ++m)
#pragma unroll
            for (int ct = 0; ct < 2; ++ct)
                oacc[hh][m][ct] = __builtin_amdgcn_mfma_f32_16x16x32_bf16(pa[m], hb[ct], oacc[hh][m][ct], 0, 0, 0);
    }

    // ---- store: D layout col = l&15 (f), row = kq*4+q (+16m) = node ----
    float* ob = out + (size_t)b * (NNODE * HF);
#pragma unroll
    for (int hh = 0; hh < 2; ++hh) {
        const int h = 2 * w + hh;
#pragma unroll
        for (int ct = 0; ct < 2; ++ct) {
            const int colf = h * 32 + ct * 16 + r;
            const float bv = sBias[colf];
#pragma unroll
            for (int m = 0; m < 2; ++m)
#pragma unroll
                for (int q = 0; q < 4; ++q) {
                    const int node = 16 * m + kq * 4 + q;
                    if (node < NNODE)
                        ob[node * HF + colf] = oacc[hh][m][ct][q] + bv;
                }
        }
    }
}

extern "C" void kernel_launch(void* const* d_in, const int* in_sizes, int n_in,
                              void* d_out, int out_size, void* d_ws, size_t ws_size,
                              hipStream_t stream) {
    const float* X     = (const float*)d_in[0];
    const float* W     = (const float*)d_in[1];
    const float* a_src = (const float*)d_in[2];
    const float* a_dst = (const float*)d_in[3];
    const float* bias  = (const float*)d_in[4];
    const int*   edges = (const int*)d_in[5];
    float* out = (float*)d_out;
    unsigned short* wf = (unsigned short*)d_ws;
    int* csr = (int*)((unsigned char*)d_ws + WS_CSR_OFF);

    hipLaunchKernelGGL(prep, dim3(35), dim3(256), 0, stream,
                       W, a_src, a_dst, edges, wf, csr);
    hipLaunchKernelGGL(gat_main, dim3(NBATCH), dim3(256), 0, stream,
                       X, wf, csr, bias, out);
}

// Round 6
// 174.576 us; speedup vs baseline: 1.0540x; 1.0540x over previous
//
#include <hip/hip_runtime.h>
#include <math.h>

#define NBATCH 8192
#define NNODE  25
#define DIN    256
#define NH     8
#define NF     32
#define HF     256
#define NE     48
#define NT     73     // NE + NNODE self loops
#define NEG_SLOPE 0.2f

// d_ws: [0,139264) bf16 Waug frags (17*8*64*8 shorts);
//       [139264, +4096) f32 lnm[32][32]: log(edge multiplicity), -1e30 if absent
#define WS_LNM_OFF 139264

typedef __bf16 bf16x8 __attribute__((ext_vector_type(8)));
typedef float  f32x4  __attribute__((ext_vector_type(4)));

static __device__ __forceinline__ unsigned short f2bf(float f) {
    unsigned int u = __float_as_uint(f);
    return (unsigned short)((u + 0x7fffu + ((u >> 16) & 1u)) >> 16);
}

static __device__ __forceinline__ float bpermf(int idxb, float v) {
    return __int_as_float(__builtin_amdgcn_ds_bpermute(idxb, __float_as_int(v)));
}

// ---- prep: pack Waug B-frags (blocks 0..33, unchanged/verified) + lnm table ----
__global__ void prep(const float* __restrict__ W,
                     const float* __restrict__ a_src,
                     const float* __restrict__ a_dst,
                     const int*   __restrict__ edges,
                     unsigned short* __restrict__ wf,
                     float* __restrict__ lnm) {
    const int blk = blockIdx.x;
    if (blk < 34) {
        const int tid  = blk * 256 + threadIdx.x;   // 0..8703 == 17*8*64
        const int lane = tid & 63;
        const int ks   = (tid >> 6) & 7;
        const int ct   = tid >> 9;
        const int k0   = ks * 32 + (lane >> 4) * 8;
        if (ct < 16) {
            const int col = ct * 16 + (lane & 15);
#pragma unroll
            for (int j = 0; j < 8; ++j)
                wf[tid * 8 + j] = f2bf(W[(k0 + j) * HF + col]);
        } else {
            // tile 16: Waug[k][0..7]=W·a_src per head, [8..15]=W·a_dst per head.
            // Lane layout == A-frag of Waug^T (same per-lane layout as B-frag).
            const int hp = lane & 15;
            const float* av = (hp < 8) ? (a_src + hp * NF) : (a_dst + (hp - 8) * NF);
            const int wc = (hp & 7) * NF;
#pragma unroll
            for (int j = 0; j < 8; ++j) {
                float s = 0.f;
                for (int f = 0; f < NF; ++f)
                    s = fmaf(W[(k0 + j) * HF + wc + f], av[f], s);
                wf[tid * 8 + j] = f2bf(s);
            }
        }
    } else {
        // dense log-multiplicity adjacency: lnm[d][s]
        __shared__ int cnt[32 * 32];
        const int t = threadIdx.x;
        for (int i = t; i < 1024; i += 256) cnt[i] = 0;
        __syncthreads();
        if (t < NT) {
            const int s = (t < NE) ? edges[t]      : (t - NE);
            const int d = (t < NE) ? edges[NE + t] : (t - NE);
            atomicAdd(&cnt[d * 32 + s], 1);
        }
        __syncthreads();
        for (int i = t; i < 1024; i += 256) {
            const int c = cnt[i];
            lnm[i] = (c > 0) ? logf((float)c) : -1e30f;
        }
    }
}

// ---- main: one wave = one batch. No LDS, no barriers. ----
__global__ __launch_bounds__(64)
void gat_wave(const float* __restrict__ X,
              const unsigned short* __restrict__ wf,
              const float* __restrict__ lnm,
              const float* __restrict__ bias,
              float* __restrict__ out)
{
    const int l   = threadIdx.x;
    const int b   = blockIdx.x;
    const int r   = l & 15;
    const int kq  = l >> 4;
    const int kqa = kq & 1;
    const bool hiSel = (kq >> 1) != 0;   // m-half of node index s = kq*8+j

    // bpermute byte-index bases (lane_src * 4)
    const int idx_as_base = kqa * 32;            // + (h>>2)*64 + 4j
    const int idx_ad_base = 128 + r * 4;         // + (h>>2)*64
    const int idx_h_base  = (kqa * 32 + r) * 4;  // + (j>>2)*64

    // ---- adjacency log-mults: lnm[d = dstt*16+r][s = kq*8+j] ----
    float ln0[8], ln1[8];
    {
        const f32x4 a = *(const f32x4*)(lnm + r * 32 + kq * 8);
        const f32x4 c = *(const f32x4*)(lnm + r * 32 + kq * 8 + 4);
        const f32x4 d2 = *(const f32x4*)(lnm + (16 + r) * 32 + kq * 8);
        const f32x4 e2 = *(const f32x4*)(lnm + (16 + r) * 32 + kq * 8 + 4);
        ln0[0]=a[0]; ln0[1]=a[1]; ln0[2]=a[2]; ln0[3]=a[3];
        ln0[4]=c[0]; ln0[5]=c[1]; ln0[6]=c[2]; ln0[7]=c[3];
        ln1[0]=d2[0]; ln1[1]=d2[1]; ln1[2]=d2[2]; ln1[3]=d2[3];
        ln1[4]=e2[0]; ln1[5]=e2[1]; ln1[6]=e2[2]; ln1[7]=e2[3];
    }

    // ---- A-frags straight from global: af{m}[ks] = X[16m+r][ks*32+kq*8 .. +7] ----
    bf16x8 af0[8], af1[8];
    const float* Xb = X + (size_t)b * (NNODE * DIN);
    {
        const float* xp0 = Xb + r * DIN + kq * 8;
#pragma unroll
        for (int ks = 0; ks < 8; ++ks) {
            const f32x4 x0 = *(const f32x4*)(xp0 + ks * 32);
            const f32x4 x1 = *(const f32x4*)(xp0 + ks * 32 + 4);
            bf16x8 v;
            v[0]=(__bf16)x0[0]; v[1]=(__bf16)x0[1]; v[2]=(__bf16)x0[2]; v[3]=(__bf16)x0[3];
            v[4]=(__bf16)x1[0]; v[5]=(__bf16)x1[1]; v[6]=(__bf16)x1[2]; v[7]=(__bf16)x1[3];
            af0[ks] = v;
        }
        const bool valid = r < 9;                 // rows 16+r must be < 25
        const float zm = valid ? 1.f : 0.f;
        const float* xp1 = Xb + (valid ? (16 + r) : r) * DIN + kq * 8;
#pragma unroll
        for (int ks = 0; ks < 8; ++ks) {
            const f32x4 x0 = *(const f32x4*)(xp1 + ks * 32);
            const f32x4 x1 = *(const f32x4*)(xp1 + ks * 32 + 4);
            bf16x8 v;
            v[0]=(__bf16)(x0[0]*zm); v[1]=(__bf16)(x0[1]*zm); v[2]=(__bf16)(x0[2]*zm); v[3]=(__bf16)(x0[3]*zm);
            v[4]=(__bf16)(x1[0]*zm); v[5]=(__bf16)(x1[1]*zm); v[6]=(__bf16)(x1[2]*zm); v[7]=(__bf16)(x1[3]*zm);
            af1[ks] = v;
        }
    }

    // ---- logits, swapped: L^T = Wa^T · X^T  =>  accL{m}[q] = L[16m+r][head-col 4kq+q] ----
    f32x4 accL0 = {0.f, 0.f, 0.f, 0.f};
    f32x4 accL1 = {0.f, 0.f, 0.f, 0.f};
#pragma unroll
    for (int ks = 0; ks < 8; ++ks) {
        const bf16x8 wa = *(const bf16x8*)(wf + ((size_t)(128 + ks) * 64 + l) * 8);
        accL0 = __builtin_amdgcn_mfma_f32_16x16x32_bf16(wa, af0[ks], accL0, 0, 0, 0);
        accL1 = __builtin_amdgcn_mfma_f32_16x16x32_bf16(wa, af1[ks], accL1, 0, 0, 0);
    }

    float* ob = out + (size_t)b * (NNODE * HF);

#pragma unroll
    for (int h = 0; h < 8; ++h) {
        // ---- softmax for head h: P^T B-frags pf{dstt}[j] = alpha[dstt*16+r][kq*8+j] ----
        const int hb = (h >> 2) * 64;
        const int q  = h & 3;                       // accL register holding head h (static)
        const float ad0 = bpermf(idx_ad_base + hb, accL0[q]);   // L[d=r][8+h]
        const float ad1 = bpermf(idx_ad_base + hb, accL1[q]);   // L[d=16+r][8+h]
        float e0[8], e1[8];
        float s0 = 0.f, s1 = 0.f;
#pragma unroll
        for (int j = 0; j < 8; ++j) {
            const int ia = idx_as_base + hb + j * 4;
            const float v0 = bpermf(ia, accL0[q]);
            const float v1 = bpermf(ia, accL1[q]);
            const float asj = hiSel ? v1 : v0;      // as[s = kq*8+j][h]
            float t0 = asj + ad0; t0 = (t0 > 0.f) ? t0 : NEG_SLOPE * t0;
            float t1 = asj + ad1; t1 = (t1 > 0.f) ? t1 : NEG_SLOPE * t1;
            e0[j] = __expf(t0 + ln0[j]);            // mult * exp(leaky), 0 if no edge
            e1[j] = __expf(t1 + ln1[j]);
            s0 += e0[j]; s1 += e1[j];
        }
        s0 += __shfl_xor(s0, 16); s0 += __shfl_xor(s0, 32);
        s1 += __shfl_xor(s1, 16); s1 += __shfl_xor(s1, 32);
        const float i0 = 1.f / (s0 + 1e-16f);
        const float i1 = 1.f / (s1 + 1e-16f);
        bf16x8 pf0, pf1;
#pragma unroll
        for (int j = 0; j < 8; ++j) {
            pf0[j] = (__bf16)(e0[j] * i0);
            pf1[j] = (__bf16)(e1[j] * i1);
        }

        // ---- two 16-col feature tiles of this head ----
#pragma unroll
        for (int cc = 0; cc < 2; ++cc) {
            const int ct = 2 * h + cc;
            // GEMM1: h columns ct*16..+15. acc{m}[q'] = h[16m+4kq+q'][ct*16+r]
            f32x4 a0 = {0.f, 0.f, 0.f, 0.f};
            f32x4 a1 = {0.f, 0.f, 0.f, 0.f};
#pragma unroll
            for (int ks = 0; ks < 8; ++ks) {
                const bf16x8 bw = *(const bf16x8*)(wf + ((size_t)(ct * 8 + ks) * 64 + l) * 8);
                a0 = __builtin_amdgcn_mfma_f32_16x16x32_bf16(af0[ks], bw, a0, 0, 0, 0);
                a1 = __builtin_amdgcn_mfma_f32_16x16x32_bf16(af1[ks], bw, a1, 0, 0, 0);
            }
            // redistribute -> GEMM2 A-frag: hf[j] = h[s = kq*8+j][feat = ct*16+r]
            bf16x8 hf;
#pragma unroll
            for (int j = 0; j < 8; ++j) {
                const int ih = idx_h_base + (j >> 2) * 64;
                const float v0 = bpermf(ih, a0[j & 3]);
                const float v1 = bpermf(ih, a1[j & 3]);
                hf[j] = (__bf16)(hiSel ? v1 : v0);
            }
            // GEMM2: out^T tile = h^T · P^T (+bias as C-in), K=32 one-shot
            const f32x4 bv = *(const f32x4*)(bias + ct * 16 + kq * 4);
            f32x4 o0 = bv, o1 = bv;
            o0 = __builtin_amdgcn_mfma_f32_16x16x32_bf16(hf, pf0, o0, 0, 0, 0);
            o1 = __builtin_amdgcn_mfma_f32_16x16x32_bf16(hf, pf1, o1, 0, 0, 0);
            // D[row = feat-in-tile 4kq+q'][col = dst r] -> out[b][dst][16ct+4kq+q']
            *(f32x4*)(ob + r * HF + ct * 16 + kq * 4) = o0;
            if (r < 9)
                *(f32x4*)(ob + (16 + r) * HF + ct * 16 + kq * 4) = o1;
        }
    }
}

extern "C" void kernel_launch(void* const* d_in, const int* in_sizes, int n_in,
                              void* d_out, int out_size, void* d_ws, size_t ws_size,
                              hipStream_t stream) {
    const float* X     = (const float*)d_in[0];
    const float* W     = (const float*)d_in[1];
    const float* a_src = (const float*)d_in[2];
    const float* a_dst = (const float*)d_in[3];
    const float* bias  = (const float*)d_in[4];
    const int*   edges = (const int*)d_in[5];
    float* out = (float*)d_out;
    unsigned short* wf = (unsigned short*)d_ws;
    float* lnm = (float*)((unsigned char*)d_ws + WS_LNM_OFF);

    hipLaunchKernelGGL(prep, dim3(35), dim3(256), 0, stream,
                       W, a_src, a_dst, edges, wf, lnm);
    hipLaunchKernelGGL(gat_wave, dim3(NBATCH), dim3(64), 0, stream,
                       X, wf, lnm, bias, out);
}

// Round 7
// 173.425 us; speedup vs baseline: 1.0610x; 1.0066x over previous
//
#include <hip/hip_runtime.h>
#include <math.h>

#define NBATCH 8192
#define NNODE  25
#define DIN    256
#define NH     8
#define NF     32
#define HF     256
#define NE     48
#define NT     73     // NE + NNODE self loops
#define NEG_SLOPE 0.2f

// d_ws: [0,139264) bf16 Waug frags (17*8*64*8 shorts);
//       [139264, +4096) f32 lnm[32][32]: log(edge multiplicity), -1e30 if absent
#define WS_LNM_OFF 139264

typedef __bf16 bf16x8 __attribute__((ext_vector_type(8)));
typedef float  f32x4  __attribute__((ext_vector_type(4)));

static __device__ __forceinline__ unsigned short f2bf(float f) {
    unsigned int u = __float_as_uint(f);
    return (unsigned short)((u + 0x7fffu + ((u >> 16) & 1u)) >> 16);
}

static __device__ __forceinline__ float bpermf(int idxb, float v) {
    return __int_as_float(__builtin_amdgcn_ds_bpermute(idxb, __float_as_int(v)));
}

// ---- prep: pack Waug B-frags (blocks 0..33, verified) + lnm table ----
__global__ void prep(const float* __restrict__ W,
                     const float* __restrict__ a_src,
                     const float* __restrict__ a_dst,
                     const int*   __restrict__ edges,
                     unsigned short* __restrict__ wf,
                     float* __restrict__ lnm) {
    const int blk = blockIdx.x;
    if (blk < 34) {
        const int tid  = blk * 256 + threadIdx.x;   // 0..8703 == 17*8*64
        const int lane = tid & 63;
        const int ks   = (tid >> 6) & 7;
        const int ct   = tid >> 9;
        const int k0   = ks * 32 + (lane >> 4) * 8;
        if (ct < 16) {
            const int col = ct * 16 + (lane & 15);
#pragma unroll
            for (int j = 0; j < 8; ++j)
                wf[tid * 8 + j] = f2bf(W[(k0 + j) * HF + col]);
        } else {
            // tile 16: Waug[k][0..7]=W·a_src per head, [8..15]=W·a_dst per head.
            const int hp = lane & 15;
            const float* av = (hp < 8) ? (a_src + hp * NF) : (a_dst + (hp - 8) * NF);
            const int wc = (hp & 7) * NF;
#pragma unroll
            for (int j = 0; j < 8; ++j) {
                float s = 0.f;
                for (int f = 0; f < NF; ++f)
                    s = fmaf(W[(k0 + j) * HF + wc + f], av[f], s);
                wf[tid * 8 + j] = f2bf(s);
            }
        }
    } else {
        // dense log-multiplicity adjacency: lnm[d][s]
        __shared__ int cnt[32 * 32];
        const int t = threadIdx.x;
        for (int i = t; i < 1024; i += 256) cnt[i] = 0;
        __syncthreads();
        if (t < NT) {
            const int s = (t < NE) ? edges[t]      : (t - NE);
            const int d = (t < NE) ? edges[NE + t] : (t - NE);
            atomicAdd(&cnt[d * 32 + s], 1);
        }
        __syncthreads();
        for (int i = t; i < 1024; i += 256) {
            const int c = cnt[i];
            lnm[i] = (c > 0) ? logf((float)c) : -1e30f;
        }
    }
}

// ---- main: one wave = one batch; 4 independent waves per workgroup.
//      No LDS, no barriers (waves never interact). ----
__global__ __launch_bounds__(256)
void gat_wave(const float* __restrict__ X,
              const unsigned short* __restrict__ wf,
              const float* __restrict__ lnm,
              const float* __restrict__ bias,
              float* __restrict__ out)
{
    const int t   = threadIdx.x;
    const int l   = t & 63;
    const int b   = blockIdx.x * 4 + (t >> 6);
    const int r   = l & 15;
    const int kq  = l >> 4;
    const int kqa = kq & 1;
    const bool hiSel = (kq >> 1) != 0;   // m-half of node index s = kq*8+j

    // bpermute byte-index bases (lane_src * 4)
    const int idx_as_base = kqa * 32;            // + (h>>2)*64 + 4j
    const int idx_ad_base = 128 + r * 4;         // + (h>>2)*64
    const int idx_h_base  = (kqa * 32 + r) * 4;  // + (j>>2)*64

    // ---- adjacency log-mults: lnm[d = dstt*16+r][s = kq*8+j] ----
    float ln0[8], ln1[8];
    {
        const f32x4 a = *(const f32x4*)(lnm + r * 32 + kq * 8);
        const f32x4 c = *(const f32x4*)(lnm + r * 32 + kq * 8 + 4);
        const f32x4 d2 = *(const f32x4*)(lnm + (16 + r) * 32 + kq * 8);
        const f32x4 e2 = *(const f32x4*)(lnm + (16 + r) * 32 + kq * 8 + 4);
        ln0[0]=a[0]; ln0[1]=a[1]; ln0[2]=a[2]; ln0[3]=a[3];
        ln0[4]=c[0]; ln0[5]=c[1]; ln0[6]=c[2]; ln0[7]=c[3];
        ln1[0]=d2[0]; ln1[1]=d2[1]; ln1[2]=d2[2]; ln1[3]=d2[3];
        ln1[4]=e2[0]; ln1[5]=e2[1]; ln1[6]=e2[2]; ln1[7]=e2[3];
    }

    // ---- A-frags straight from global: af{m}[ks] = X[16m+r][ks*32+kq*8 .. +7] ----
    bf16x8 af0[8], af1[8];
    const float* Xb = X + (size_t)b * (NNODE * DIN);
    {
        const float* xp0 = Xb + r * DIN + kq * 8;
#pragma unroll
        for (int ks = 0; ks < 8; ++ks) {
            const f32x4 x0 = *(const f32x4*)(xp0 + ks * 32);
            const f32x4 x1 = *(const f32x4*)(xp0 + ks * 32 + 4);
            bf16x8 v;
            v[0]=(__bf16)x0[0]; v[1]=(__bf16)x0[1]; v[2]=(__bf16)x0[2]; v[3]=(__bf16)x0[3];
            v[4]=(__bf16)x1[0]; v[5]=(__bf16)x1[1]; v[6]=(__bf16)x1[2]; v[7]=(__bf16)x1[3];
            af0[ks] = v;
        }
        const bool valid = r < 9;                 // rows 16+r must be < 25
        const float zm = valid ? 1.f : 0.f;
        const float* xp1 = Xb + (valid ? (16 + r) : r) * DIN + kq * 8;
#pragma unroll
        for (int ks = 0; ks < 8; ++ks) {
            const f32x4 x0 = *(const f32x4*)(xp1 + ks * 32);
            const f32x4 x1 = *(const f32x4*)(xp1 + ks * 32 + 4);
            bf16x8 v;
            v[0]=(__bf16)(x0[0]*zm); v[1]=(__bf16)(x0[1]*zm); v[2]=(__bf16)(x0[2]*zm); v[3]=(__bf16)(x0[3]*zm);
            v[4]=(__bf16)(x1[0]*zm); v[5]=(__bf16)(x1[1]*zm); v[6]=(__bf16)(x1[2]*zm); v[7]=(__bf16)(x1[3]*zm);
            af1[ks] = v;
        }
    }

    // ---- logits, swapped: L^T = Wa^T · X^T  =>  accL{m}[q] = L[16m+r][head-col 4kq+q] ----
    f32x4 accL0 = {0.f, 0.f, 0.f, 0.f};
    f32x4 accL1 = {0.f, 0.f, 0.f, 0.f};
#pragma unroll
    for (int ks = 0; ks < 8; ++ks) {
        const bf16x8 wa = *(const bf16x8*)(wf + ((size_t)(128 + ks) * 64 + l) * 8);
        accL0 = __builtin_amdgcn_mfma_f32_16x16x32_bf16(wa, af0[ks], accL0, 0, 0, 0);
        accL1 = __builtin_amdgcn_mfma_f32_16x16x32_bf16(wa, af1[ks], accL1, 0, 0, 0);
    }

    float* ob = out + (size_t)b * (NNODE * HF);

#pragma unroll
    for (int h = 0; h < 8; ++h) {
        // ---- softmax for head h: P^T B-frags pf{dstt}[j] = alpha[dstt*16+r][kq*8+j] ----
        const int hb = (h >> 2) * 64;
        const int q  = h & 3;                       // accL register holding head h (static)
        const float ad0 = bpermf(idx_ad_base + hb, accL0[q]);   // L[d=r][8+h]
        const float ad1 = bpermf(idx_ad_base + hb, accL1[q]);   // L[d=16+r][8+h]
        float e0[8], e1[8];
        float s0 = 0.f, s1 = 0.f;
#pragma unroll
        for (int j = 0; j < 8; ++j) {
            const int ia = idx_as_base + hb + j * 4;
            const float v0 = bpermf(ia, accL0[q]);
            const float v1 = bpermf(ia, accL1[q]);
            const float asj = hiSel ? v1 : v0;      // as[s = kq*8+j][h]
            float t0 = asj + ad0; t0 = (t0 > 0.f) ? t0 : NEG_SLOPE * t0;
            float t1 = asj + ad1; t1 = (t1 > 0.f) ? t1 : NEG_SLOPE * t1;
            e0[j] = __expf(t0 + ln0[j]);            // mult * exp(leaky), 0 if no edge
            e1[j] = __expf(t1 + ln1[j]);
            s0 += e0[j]; s1 += e1[j];
        }
        s0 += __shfl_xor(s0, 16); s0 += __shfl_xor(s0, 32);
        s1 += __shfl_xor(s1, 16); s1 += __shfl_xor(s1, 32);
        const float i0 = 1.f / (s0 + 1e-16f);
        const float i1 = 1.f / (s1 + 1e-16f);
        bf16x8 pf0, pf1;
#pragma unroll
        for (int j = 0; j < 8; ++j) {
            pf0[j] = (__bf16)(e0[j] * i0);
            pf1[j] = (__bf16)(e1[j] * i1);
        }

        // ---- two 16-col feature tiles of this head ----
#pragma unroll
        for (int cc = 0; cc < 2; ++cc) {
            const int ct = 2 * h + cc;
            // GEMM1: h columns ct*16..+15. acc{m}[q'] = h[16m+4kq+q'][ct*16+r]
            f32x4 a0 = {0.f, 0.f, 0.f, 0.f};
            f32x4 a1 = {0.f, 0.f, 0.f, 0.f};
#pragma unroll
            for (int ks = 0; ks < 8; ++ks) {
                const bf16x8 bw = *(const bf16x8*)(wf + ((size_t)(ct * 8 + ks) * 64 + l) * 8);
                a0 = __builtin_amdgcn_mfma_f32_16x16x32_bf16(af0[ks], bw, a0, 0, 0, 0);
                a1 = __builtin_amdgcn_mfma_f32_16x16x32_bf16(af1[ks], bw, a1, 0, 0, 0);
            }
            // redistribute -> GEMM2 A-frag: hf[j] = h[s = kq*8+j][feat = ct*16+r]
            bf16x8 hf;
#pragma unroll
            for (int j = 0; j < 8; ++j) {
                const int ih = idx_h_base + (j >> 2) * 64;
                const float v0 = bpermf(ih, a0[j & 3]);
                const float v1 = bpermf(ih, a1[j & 3]);
                hf[j] = (__bf16)(hiSel ? v1 : v0);
            }
            // GEMM2: out^T tile = h^T · P^T (+bias as C-in), K=32 one-shot
            const f32x4 bv = *(const f32x4*)(bias + ct * 16 + kq * 4);
            f32x4 o0 = bv, o1 = bv;
            o0 = __builtin_amdgcn_mfma_f32_16x16x32_bf16(hf, pf0, o0, 0, 0, 0);
            o1 = __builtin_amdgcn_mfma_f32_16x16x32_bf16(hf, pf1, o1, 0, 0, 0);
            // D[row = feat-in-tile 4kq+q'][col = dst r] -> out[b][dst][16ct+4kq+q']
            *(f32x4*)(ob + r * HF + ct * 16 + kq * 4) = o0;
            if (r < 9)
                *(f32x4*)(ob + (16 + r) * HF + ct * 16 + kq * 4) = o1;
        }
    }
}

extern "C" void kernel_launch(void* const* d_in, const int* in_sizes, int n_in,
                              void* d_out, int out_size, void* d_ws, size_t ws_size,
                              hipStream_t stream) {
    const float* X     = (const float*)d_in[0];
    const float* W     = (const float*)d_in[1];
    const float* a_src = (const float*)d_in[2];
    const float* a_dst = (const float*)d_in[3];
    const float* bias  = (const float*)d_in[4];
    const int*   edges = (const int*)d_in[5];
    float* out = (float*)d_out;
    unsigned short* wf = (unsigned short*)d_ws;
    float* lnm = (float*)((unsigned char*)d_ws + WS_LNM_OFF);

    hipLaunchKernelGGL(prep, dim3(35), dim3(256), 0, stream,
                       W, a_src, a_dst, edges, wf, lnm);
    hipLaunchKernelGGL(gat_wave, dim3(NBATCH / 4), dim3(256), 0, stream,
                       X, wf, lnm, bias, out);
}

// Round 8
// 158.326 us; speedup vs baseline: 1.1622x; 1.0954x over previous
//
#include <hip/hip_runtime.h>
#include <math.h>

#define NBATCH 8192
#define NNODE  25
#define DIN    256
#define NH     8
#define NF     32
#define HF     256
#define NE     48
#define NT     73     // NE + NNODE self loops
#define NEG_SLOPE 0.2f

// d_ws: [0,139264) bf16 Waug frags (17*8*64*8 shorts);
//       [139264, +4096) f32 lnm[32][32]: log(edge multiplicity), -1e30 if absent
#define WS_LNM_OFF 139264

typedef __bf16 bf16x8 __attribute__((ext_vector_type(8)));
typedef float  f32x4  __attribute__((ext_vector_type(4)));

static __device__ __forceinline__ unsigned short f2bf(float f) {
    unsigned int u = __float_as_uint(f);
    return (unsigned short)((u + 0x7fffu + ((u >> 16) & 1u)) >> 16);
}

static __device__ __forceinline__ float bpermf(int idxb, float v) {
    return __int_as_float(__builtin_amdgcn_ds_bpermute(idxb, __float_as_int(v)));
}

// ---- prep: pack Waug B-frags (blocks 0..33, verified) + lnm table ----
__global__ void prep(const float* __restrict__ W,
                     const float* __restrict__ a_src,
                     const float* __restrict__ a_dst,
                     const int*   __restrict__ edges,
                     unsigned short* __restrict__ wf,
                     float* __restrict__ lnm) {
    const int blk = blockIdx.x;
    if (blk < 34) {
        const int tid  = blk * 256 + threadIdx.x;   // 0..8703 == 17*8*64
        const int lane = tid & 63;
        const int ks   = (tid >> 6) & 7;
        const int ct   = tid >> 9;
        const int k0   = ks * 32 + (lane >> 4) * 8;
        if (ct < 16) {
            const int col = ct * 16 + (lane & 15);
#pragma unroll
            for (int j = 0; j < 8; ++j)
                wf[tid * 8 + j] = f2bf(W[(k0 + j) * HF + col]);
        } else {
            // tile 16: Waug[k][0..7]=W·a_src per head, [8..15]=W·a_dst per head.
            const int hp = lane & 15;
            const float* av = (hp < 8) ? (a_src + hp * NF) : (a_dst + (hp - 8) * NF);
            const int wc = (hp & 7) * NF;
#pragma unroll
            for (int j = 0; j < 8; ++j) {
                float s = 0.f;
                for (int f = 0; f < NF; ++f)
                    s = fmaf(W[(k0 + j) * HF + wc + f], av[f], s);
                wf[tid * 8 + j] = f2bf(s);
            }
        }
    } else {
        // dense log-multiplicity adjacency: lnm[d][s]
        __shared__ int cnt[32 * 32];
        const int t = threadIdx.x;
        for (int i = t; i < 1024; i += 256) cnt[i] = 0;
        __syncthreads();
        if (t < NT) {
            const int s = (t < NE) ? edges[t]      : (t - NE);
            const int d = (t < NE) ? edges[NE + t] : (t - NE);
            atomicAdd(&cnt[d * 32 + s], 1);
        }
        __syncthreads();
        for (int i = t; i < 1024; i += 256) {
            const int c = cnt[i];
            lnm[i] = (c > 0) ? logf((float)c) : -1e30f;
        }
    }
}

// ---- main: one wave = one batch; 4 independent waves per workgroup.
//      No LDS, no barriers. launch_bounds(256,3): 170-VGPR budget -> NO SPILLS
//      (the whole-kernel live state ~135 regs; the default 80-reg allocation
//      was spilling/remat'ing ~50 regs per head-iteration = the 90% stall). ----
__global__ __launch_bounds__(256, 3)
void gat_wave(const float* __restrict__ X,
              const unsigned short* __restrict__ wf,
              const float* __restrict__ lnm,
              const float* __restrict__ bias,
              float* __restrict__ out)
{
    const int t   = threadIdx.x;
    const int l   = t & 63;
    const int b   = blockIdx.x * 4 + (t >> 6);
    const int r   = l & 15;
    const int kq  = l >> 4;
    const int kqa = kq & 1;
    const bool hiSel = (kq >> 1) != 0;   // m-half of node index s = kq*8+j

    // bpermute byte-index bases (lane_src * 4)
    const int idx_as_base = kqa * 32;            // + (h>>2)*64 + 4j
    const int idx_ad_base = 128 + r * 4;         // + (h>>2)*64
    const int idx_h_base  = (kqa * 32 + r) * 4;  // + (j>>2)*64

    // ---- A-frags straight from global: af{m}[ks] = X[16m+r][ks*32+kq*8 .. +7] ----
    bf16x8 af0[8], af1[8];
    const float* Xb = X + (size_t)b * (NNODE * DIN);
    {
        const float* xp0 = Xb + r * DIN + kq * 8;
#pragma unroll
        for (int ks = 0; ks < 8; ++ks) {
            const f32x4 x0 = *(const f32x4*)(xp0 + ks * 32);
            const f32x4 x1 = *(const f32x4*)(xp0 + ks * 32 + 4);
            bf16x8 v;
            v[0]=(__bf16)x0[0]; v[1]=(__bf16)x0[1]; v[2]=(__bf16)x0[2]; v[3]=(__bf16)x0[3];
            v[4]=(__bf16)x1[0]; v[5]=(__bf16)x1[1]; v[6]=(__bf16)x1[2]; v[7]=(__bf16)x1[3];
            af0[ks] = v;
        }
        const bool valid = r < 9;                 // rows 16+r must be < 25
        const float zm = valid ? 1.f : 0.f;
        const float* xp1 = Xb + (valid ? (16 + r) : r) * DIN + kq * 8;
#pragma unroll
        for (int ks = 0; ks < 8; ++ks) {
            const f32x4 x0 = *(const f32x4*)(xp1 + ks * 32);
            const f32x4 x1 = *(const f32x4*)(xp1 + ks * 32 + 4);
            bf16x8 v;
            v[0]=(__bf16)(x0[0]*zm); v[1]=(__bf16)(x0[1]*zm); v[2]=(__bf16)(x0[2]*zm); v[3]=(__bf16)(x0[3]*zm);
            v[4]=(__bf16)(x1[0]*zm); v[5]=(__bf16)(x1[1]*zm); v[6]=(__bf16)(x1[2]*zm); v[7]=(__bf16)(x1[3]*zm);
            af1[ks] = v;
        }
    }

    // ---- logits, swapped: L^T = Wa^T · X^T  =>  accL{m}[q] = L[16m+r][head-col 4kq+q] ----
    f32x4 accL0 = {0.f, 0.f, 0.f, 0.f};
    f32x4 accL1 = {0.f, 0.f, 0.f, 0.f};
#pragma unroll
    for (int ks = 0; ks < 8; ++ks) {
        const bf16x8 wa = *(const bf16x8*)(wf + ((size_t)(128 + ks) * 64 + l) * 8);
        accL0 = __builtin_amdgcn_mfma_f32_16x16x32_bf16(wa, af0[ks], accL0, 0, 0, 0);
        accL1 = __builtin_amdgcn_mfma_f32_16x16x32_bf16(wa, af1[ks], accL1, 0, 0, 0);
    }

    float* ob = out + (size_t)b * (NNODE * HF);

#pragma unroll
    for (int h = 0; h < 8; ++h) {
        // ---- adjacency log-mults reloaded per head (L2-hot, frees 16 VGPRs) ----
        // lnm[d = dstt*16+r][s = kq*8+j]
        const f32x4 lnA0 = *(const f32x4*)(lnm + r * 32 + kq * 8);
        const f32x4 lnA1 = *(const f32x4*)(lnm + r * 32 + kq * 8 + 4);
        const f32x4 lnB0 = *(const f32x4*)(lnm + (16 + r) * 32 + kq * 8);
        const f32x4 lnB1 = *(const f32x4*)(lnm + (16 + r) * 32 + kq * 8 + 4);

        // ---- softmax for head h: P^T B-frags pf{dstt}[j] = alpha[dstt*16+r][kq*8+j] ----
        const int hb = (h >> 2) * 64;
        const int q  = h & 3;                       // accL register holding head h (static)
        const float ad0 = bpermf(idx_ad_base + hb, accL0[q]);   // L[d=r][8+h]
        const float ad1 = bpermf(idx_ad_base + hb, accL1[q]);   // L[d=16+r][8+h]
        float e0[8], e1[8];
        float s0 = 0.f, s1 = 0.f;
#pragma unroll
        for (int j = 0; j < 8; ++j) {
            const int ia = idx_as_base + hb + j * 4;
            const float v0 = bpermf(ia, accL0[q]);
            const float v1 = bpermf(ia, accL1[q]);
            const float asj = hiSel ? v1 : v0;      // as[s = kq*8+j][h]
            const float ln0j = (j < 4) ? lnA0[j & 3] : lnA1[j & 3];
            const float ln1j = (j < 4) ? lnB0[j & 3] : lnB1[j & 3];
            float t0 = asj + ad0; t0 = (t0 > 0.f) ? t0 : NEG_SLOPE * t0;
            float t1 = asj + ad1; t1 = (t1 > 0.f) ? t1 : NEG_SLOPE * t1;
            e0[j] = __expf(t0 + ln0j);              // mult * exp(leaky), 0 if no edge
            e1[j] = __expf(t1 + ln1j);
            s0 += e0[j]; s1 += e1[j];
        }
        s0 += __shfl_xor(s0, 16); s0 += __shfl_xor(s0, 32);
        s1 += __shfl_xor(s1, 16); s1 += __shfl_xor(s1, 32);
        const float i0 = 1.f / (s0 + 1e-16f);
        const float i1 = 1.f / (s1 + 1e-16f);
        bf16x8 pf0, pf1;
#pragma unroll
        for (int j = 0; j < 8; ++j) {
            pf0[j] = (__bf16)(e0[j] * i0);
            pf1[j] = (__bf16)(e1[j] * i1);
        }

        // ---- two 16-col feature tiles of this head ----
#pragma unroll
        for (int cc = 0; cc < 2; ++cc) {
            const int ct = 2 * h + cc;
            // GEMM1: h columns ct*16..+15. acc{m}[q'] = h[16m+4kq+q'][ct*16+r]
            f32x4 a0 = {0.f, 0.f, 0.f, 0.f};
            f32x4 a1 = {0.f, 0.f, 0.f, 0.f};
#pragma unroll
            for (int ks = 0; ks < 8; ++ks) {
                const bf16x8 bw = *(const bf16x8*)(wf + ((size_t)(ct * 8 + ks) * 64 + l) * 8);
                a0 = __builtin_amdgcn_mfma_f32_16x16x32_bf16(af0[ks], bw, a0, 0, 0, 0);
                a1 = __builtin_amdgcn_mfma_f32_16x16x32_bf16(af1[ks], bw, a1, 0, 0, 0);
            }
            // redistribute -> GEMM2 A-frag: hf[j] = h[s = kq*8+j][feat = ct*16+r]
            bf16x8 hf;
#pragma unroll
            for (int j = 0; j < 8; ++j) {
                const int ih = idx_h_base + (j >> 2) * 64;
                const float v0 = bpermf(ih, a0[j & 3]);
                const float v1 = bpermf(ih, a1[j & 3]);
                hf[j] = (__bf16)(hiSel ? v1 : v0);
            }
            // GEMM2: out^T tile = h^T · P^T (+bias as C-in), K=32 one-shot
            const f32x4 bv = *(const f32x4*)(bias + ct * 16 + kq * 4);
            f32x4 o0 = bv, o1 = bv;
            o0 = __builtin_amdgcn_mfma_f32_16x16x32_bf16(hf, pf0, o0, 0, 0, 0);
            o1 = __builtin_amdgcn_mfma_f32_16x16x32_bf16(hf, pf1, o1, 0, 0, 0);
            // D[row = feat-in-tile 4kq+q'][col = dst r] -> out[b][dst][16ct+4kq+q']
            *(f32x4*)(ob + r * HF + ct * 16 + kq * 4) = o0;
            if (r < 9)
                *(f32x4*)(ob + (16 + r) * HF + ct * 16 + kq * 4) = o1;
        }
    }
}

extern "C" void kernel_launch(void* const* d_in, const int* in_sizes, int n_in,
                              void* d_out, int out_size, void* d_ws, size_t ws_size,
                              hipStream_t stream) {
    const float* X     = (const float*)d_in[0];
    const float* W     = (const float*)d_in[1];
    const float* a_src = (const float*)d_in[2];
    const float* a_dst = (const float*)d_in[3];
    const float* bias  = (const float*)d_in[4];
    const int*   edges = (const int*)d_in[5];
    float* out = (float*)d_out;
    unsigned short* wf = (unsigned short*)d_ws;
    float* lnm = (float*)((unsigned char*)d_ws + WS_LNM_OFF);

    hipLaunchKernelGGL(prep, dim3(35), dim3(256), 0, stream,
                       W, a_src, a_dst, edges, wf, lnm);
    hipLaunchKernelGGL(gat_wave, dim3(NBATCH / 4), dim3(256), 0, stream,
                       X, wf, lnm, bias, out);
}